// Round 12
// baseline (244.073 us; speedup 1.0000x reference)
//
#include <hip/hip_runtime.h>
#include <hip/hip_bf16.h>

// B=64, T=2048, D=784, N1=100, N2=10, dt=0.04
// Pipeline:
//   prep_w3  : W1 -> fp16 2-way split (h, r*1024), per-K-tile image
//              [kt=25][18432 B]: [term 2][n 112][40 shorts(32 data+8 pad)] + 512 B pad
//   gemm1_p  : z1 = batch @ W1^T, 3-term fp16 split MFMA 16x16x32 (proven layout,
//              round-11 BODY verbatim). NEW: 128-thread blocks (2 waves), BM=64,
//              grid 2048 -> 4 independent barrier domains per CU (vs 2) at the
//              same 8 waves/CU, so stage/compute phases of different blocks
//              interleave (breaks the serial-sum lockstep of r6/r11).
//   fused_scan: scan1 + gemm2 + scan2 in one kernel (round-6/7/11 version verbatim).
//
// ws: Wg 460800 B | z1p 131072*100 f32 (52.4 MB)

#define FHN_DT 0.04f

typedef _Float16 f16x8 __attribute__((ext_vector_type(8)));
typedef __attribute__((ext_vector_type(4))) float          f32x4;
typedef __attribute__((ext_vector_type(8))) unsigned short ushort8;

__device__ __forceinline__ void sync_lds() {
    asm volatile("s_waitcnt lgkmcnt(0)" ::: "memory");
    __builtin_amdgcn_s_barrier();
    asm volatile("" ::: "memory");
}

// ---------------- prep: W1 (100x784) -> tiled fp16 2-term split image ----------------
// tile = 9216 shorts (18432 B): [term 2][n 112][40 shorts] = 8960 + 256 pad (zeros)
__global__ void prep_w3(const float* __restrict__ W1, unsigned short* __restrict__ Wg) {
    int idx = blockIdx.x * 256 + threadIdx.x;     // < 25*9216 = 230400
    if (idx >= 230400) return;
    int kt  = idx / 9216;
    int rem = idx % 9216;
    unsigned short v16 = 0;
    if (rem < 8960) {
        int term = rem / 4480;
        int r2   = rem % 4480;
        int n    = r2 / 40;
        int sh   = r2 % 40;
        int k    = kt * 32 + sh;
        float v = (n < 100 && sh < 32 && k < 784) ? W1[n * 784 + k] : 0.0f;
        _Float16 h = (_Float16)v;
        if (term == 0) v16 = __builtin_bit_cast(unsigned short, h);
        else           v16 = __builtin_bit_cast(unsigned short, (_Float16)((v - (float)h) * 1024.0f));
    }
    Wg[idx] = v16;
}

// ---------------- GEMM1: 3-term fp16 split, BM=64 (rt=2), BK=32, 2 waves/block ----------------
__global__ __launch_bounds__(128, 2) void gemm1_p(const float* __restrict__ A,
                                                  const unsigned short* __restrict__ Wg,
                                                  float* __restrict__ z1p) {
    __shared__ __align__(16) unsigned short Wl[2][9216];   // 36864 B -> 4 blocks/CU (LDS)
    const int tid  = threadIdx.x;                 // 0..127
    const int w    = tid >> 6;                    // 0..1
    const int lane = tid & 63;
    const int ln   = lane & 15;
    const int kg   = lane >> 4;                   // k-slice = kg*8
    const long row0 = (long)blockIdx.x * 64;

    // two A rows per lane: w*32 + ln and w*32 + 16 + ln
    const float* arow0 = A + (row0 + w * 32 + ln) * 784 + kg * 8;
    const float* arow1 = arow0 + (size_t)16 * 784;

    f32x4 acc1[2][7] = {};
    f32x4 acc2[2][7] = {};
    float afpA[16], afpB[16];       // [0..7] row0, [8..15] row1
    ushort8 wreg[9];                // 128 thr x 9 x 16 B = 18432 B tile exactly

    // A tile T into AF (k = T*32 + kg*8 + 0..7); T==24 & kg>=2 -> k>=784: zeros
#define ISSUE_A(T, AF) {                                                        \
        if ((T) == 24 && kg >= 2) {                                             \
            *(float4*)&AF[0]  = make_float4(0.f, 0.f, 0.f, 0.f);                \
            *(float4*)&AF[4]  = make_float4(0.f, 0.f, 0.f, 0.f);                \
            *(float4*)&AF[8]  = make_float4(0.f, 0.f, 0.f, 0.f);                \
            *(float4*)&AF[12] = make_float4(0.f, 0.f, 0.f, 0.f);                \
        } else {                                                                \
            *(float4*)&AF[0]  = *(const float4*)(arow0 + (T) * 32);             \
            *(float4*)&AF[4]  = *(const float4*)(arow0 + (T) * 32 + 4);         \
            *(float4*)&AF[8]  = *(const float4*)(arow1 + (T) * 32);             \
            *(float4*)&AF[12] = *(const float4*)(arow1 + (T) * 32 + 4);         \
        } }

#define LOADW(T) {                                                              \
        const char* src_ = (const char*)Wg + (size_t)(T) * 18432 + tid * 16;    \
        _Pragma("unroll")                                                       \
        for (int j_ = 0; j_ < 9; ++j_)                                          \
            wreg[j_] = *(const ushort8*)(src_ + j_ * 2048);                     \
    }

#define BODY(KT, AF) {                                                          \
        /* 1. split A (consumes AF -> compiler waits its vmem) */               \
        f16x8 ah0, al0, ah1, al1;                                               \
        _Pragma("unroll")                                                       \
        for (int e_ = 0; e_ < 8; ++e_) {                                        \
            float a0_ = AF[e_], a1_ = AF[8 + e_];                               \
            _Float16 h0_ = (_Float16)a0_, h1_ = (_Float16)a1_;                  \
            ah0[e_] = h0_; ah1[e_] = h1_;                                       \
            al0[e_] = (_Float16)((a0_ - (float)h0_) * 1024.0f);                 \
            al1[e_] = (_Float16)((a1_ - (float)h1_) * 1024.0f);                 \
        }                                                                       \
        /* 2. store W tile KT (consumes wreg -> compiler waits its vmem) */     \
        {                                                                       \
            char* buf_ = (char*)&Wl[(KT) & 1][0] + tid * 16;                    \
            _Pragma("unroll")                                                   \
            for (int j_ = 0; j_ < 9; ++j_)                                      \
                *(ushort8*)(buf_ + j_ * 2048) = wreg[j_];                       \
        }                                                                       \
        /* 3. prefetch next tiles (fly across barrier + compute) */             \
        if ((KT) < 24) LOADW((KT) + 1);                                         \
        if ((KT) < 23) ISSUE_A((KT) + 2, AF);                                   \
        /* 4. barrier: lgkmcnt only; vmem stays in flight */                    \
        sync_lds();                                                             \
        /* 5. compute: 7 ct, B-frags read ONCE, used for both rows */           \
        const unsigned short* cb_ = &Wl[(KT) & 1][0];                           \
        _Pragma("unroll")                                                       \
        for (int ct_ = 0; ct_ < 7; ++ct_) {                                     \
            const unsigned short* pw_ = cb_ + (ct_ * 16 + ln) * 40 + kg * 8;    \
            f16x8 bh = *(const f16x8*)(pw_);                                    \
            f16x8 bl = *(const f16x8*)(pw_ + 4480);                             \
            acc1[0][ct_] = __builtin_amdgcn_mfma_f32_16x16x32_f16(ah0, bh, acc1[0][ct_], 0, 0, 0); \
            acc2[0][ct_] = __builtin_amdgcn_mfma_f32_16x16x32_f16(ah0, bl, acc2[0][ct_], 0, 0, 0); \
            acc2[0][ct_] = __builtin_amdgcn_mfma_f32_16x16x32_f16(al0, bh, acc2[0][ct_], 0, 0, 0); \
            acc1[1][ct_] = __builtin_amdgcn_mfma_f32_16x16x32_f16(ah1, bh, acc1[1][ct_], 0, 0, 0); \
            acc2[1][ct_] = __builtin_amdgcn_mfma_f32_16x16x32_f16(ah1, bl, acc2[1][ct_], 0, 0, 0); \
            acc2[1][ct_] = __builtin_amdgcn_mfma_f32_16x16x32_f16(al1, bh, acc2[1][ct_], 0, 0, 0); \
        } }

    // prologue: W(0) + A(0) + A(1) into regs (first waits happen inside BODY(0))
    LOADW(0);
    ISSUE_A(0, afpA);
    ISSUE_A(1, afpB);

    for (int kt2 = 0; kt2 < 12; ++kt2) {
        BODY(kt2 * 2,     afpA);
        BODY(kt2 * 2 + 1, afpB);
    }
    BODY(24, afpA);

    // ---- epilogue: C/D map col = lane&15, row = kg*4 + r ; z = acc1 + acc2/1024 ----
#pragma unroll
    for (int ct = 0; ct < 7; ++ct) {
        int n = ct * 16 + ln;
        if (n < 100) {
#pragma unroll
            for (int rt = 0; rt < 2; ++rt) {
                long rg = row0 + w * 32 + rt * 16 + kg * 4;
                float* p = z1p + rg * 100 + n;
#pragma unroll
                for (int r = 0; r < 4; ++r)
                    p[r * 100] = fmaf(acc2[rt][ct][r], 0.0009765625f, acc1[rt][ct][r]);
            }
        }
    }
#undef ISSUE_A
#undef LOADW
#undef BODY
}

// ---------------- fused scan1 + gemm2 + scan2 (round-6/7/11 version, unchanged) ----------------
__global__ __launch_bounds__(512) void fused_scan(const float* __restrict__ z1p,
                                                  const float* __restrict__ W2,
                                                  float* __restrict__ out) {
    __shared__ float fsm[32768];
    const int tid = threadIdx.x;
    const int b   = blockIdx.x;
    const float dt = FHN_DT;

    float V = 0.f, S = 0.f;
    const float* zb = z1p + (long)b * 2048 * 100 + tid;   // scan1 lanes only
    float z0[16], z1r[16], z2r[16], z3r[16];
    if (tid < 100) {
#pragma unroll
        for (int u = 0; u < 16; ++u) {
            z0[u]  = zb[u * 100];
            z1r[u] = zb[(16 + u) * 100];
            z2r[u] = zb[(32 + u) * 100];
            z3r[u] = zb[(48 + u) * 100];
        }
    }

    const int tg = tid - 128;
    int pp = tg >> 7;                                     // wave-uniform for tid>=128
    pp = __builtin_amdgcn_readfirstlane(pp);
    const int r  = tg & 127;
    const int mb = (pp == 0) ? 0 : (pp == 1 ? 4 : 7);
    const int mc = (pp == 0) ? 4 : 3;

    for (int i = 0; i <= 18; ++i) {
        if (tid < 128) {
            bool a1 = (tid < 100) && (i < 16);
            bool a2 = (tid >= 100) && (tid < 110) && (i >= 2) && (i < 18);
            if (a1 || a2) {
                const int cw = i & 1;
#pragma unroll
                for (int sub = 0; sub < 8; ++sub) {
                    float zt[16];
                    if (a1) {
                        int tn = (i * 8 + sub + 4) * 16;
                        if (tn < 2048) {
#pragma unroll
                            for (int u = 0; u < 16; ++u) zt[u] = zb[(tn + u) * 100];
                        }
                    }
                    if (a2) {
#pragma unroll
                        for (int u = 0; u < 16; ++u)
                            z0[u] = fsm[29696 + cw * 1536 + (sub * 16 + u) * 12 + (tid - 100)];
                    }
#pragma unroll
                    for (int u = 0; u < 16; ++u) {
                        int tl = sub * 16 + u;
                        fsm[cw * 14848 + tl * 116 + tid] = V;
                        float z  = z0[u];
                        float V3 = V * V * V;
                        float Vn = fmaf(1.f + dt, V,
                                    fmaf(-dt / 3.f, V3, fmaf(-dt, S, dt * z)));
                        float Sn = fmaf(dt * 0.08f, V + 0.7f - 0.8f * S, S);
                        V = Vn; S = Sn;
                    }
                    if (a1) {
#pragma unroll
                        for (int u = 0; u < 16; ++u) {
                            z0[u] = z1r[u]; z1r[u] = z2r[u]; z2r[u] = z3r[u]; z3r[u] = zt[u];
                        }
                    }
                }
            }
        } else {
            if (i >= 1 && i <= 16) {
                const int pb = (i - 1) & 1;
                float acc[4] = {0.f, 0.f, 0.f, 0.f};
                for (int kq = 0; kq < 25; ++kq) {
                    float4 v = *(const float4*)&fsm[pb * 14848 + r * 116 + kq * 4];
#pragma unroll
                    for (int j = 0; j < 4; ++j) {
                        if (j < mc) {
                            const float* wp = W2 + (mb + j) * 100 + kq * 4;  // uniform -> s_load
                            acc[j] = fmaf(v.x, wp[0], acc[j]);
                            acc[j] = fmaf(v.y, wp[1], acc[j]);
                            acc[j] = fmaf(v.z, wp[2], acc[j]);
                            acc[j] = fmaf(v.w, wp[3], acc[j]);
                        }
                    }
                }
#pragma unroll
                for (int j = 0; j < 4; ++j)
                    if (j < mc) fsm[29696 + pb * 1536 + r * 12 + mb + j] = 0.5f * acc[j];
            }
            if (i >= 3) {
                const int pb = (i - 1) & 1;
                float* dst = out + ((long)b * 2048 + (long)(i - 3) * 128 + r) * 10;
#pragma unroll
                for (int j = 0; j < 4; ++j)
                    if (j < mc) dst[mb + j] = fsm[pb * 14848 + r * 116 + 100 + mb + j];
            }
        }
        sync_lds();
    }
}

extern "C" void kernel_launch(void* const* d_in, const int* in_sizes, int n_in,
                              void* d_out, int out_size, void* d_ws, size_t ws_size,
                              hipStream_t stream) {
    const float* batch = (const float*)d_in[0];   // 64*2048*784
    const float* W1    = (const float*)d_in[1];   // 100*784
    const float* W2    = (const float*)d_in[2];   // 10*100
    float* out = (float*)d_out;                   // 64*2048*10

    char* base = (char*)d_ws;
    unsigned short* Wg = (unsigned short*)base;   // 460800 B
    float* z1p = (float*)(base + 460800);         // 131072*100 f32

    prep_w3<<<900, 256, 0, stream>>>(W1, Wg);
    gemm1_p<<<2048, 128, 0, stream>>>(batch, Wg, z1p);
    fused_scan<<<64, 512, 0, stream>>>(z1p, W2, out);
}